// Round 6
// baseline (138.535 us; speedup 1.0000x reference)
//
#include <hip/hip_runtime.h>
#include <hip/hip_bf16.h>
#include <stdint.h>

#define NB 8192
#define ND 1024
#define SCALE 20.0f   // 1/TEMPERATURE

typedef __bf16 bf16x8 __attribute__((ext_vector_type(8)));
typedef float  f32x4  __attribute__((ext_vector_type(4)));

// ---------------- input-format detection (device-side, deterministic) -------
__device__ inline void detect_formats(const void* rel_raw, const void* ist_raw,
                                      int& rel64, int& bmode) {
  const unsigned int* r = (const unsigned int*)rel_raw;
  int is64 = 1;
  for (int i = 1; i < 256; i += 2) {
    if (r[i] != 0u) { is64 = 0; break; }
  }
  rel64 = is64;
  const unsigned int* t = (const unsigned int*)ist_raw;
  bool sawf = false, sawbig = false;
  for (int i = 0; i < 64; ++i) {
    unsigned int w = t[i];
    if (w == 0x3F800000u) sawf = true;
    else if (w > 1u) sawbig = true;
  }
  bmode = sawf ? 2 : (sawbig ? 1 : 0);
}

__device__ inline int decode_key(const void* rel_raw, const void* ist_raw,
                                 int rel64, int bmode, int i) {
  const int* r32 = (const int*)rel_raw;
  int r = rel64 ? r32[2 * i] : r32[i];
  int truth;
  if (bmode == 1)      truth = (((const unsigned char*)ist_raw)[i] != 0);
  else if (bmode == 2) truth = (((const float*)ist_raw)[i] != 0.0f);
  else                 truth = (((const int*)ist_raw)[i] != 0);
  return truth ? r : -1;
}

__device__ inline bf16x8 cvt8(const float4& a, const float4& b) {
  bf16x8 v;
  v[0] = (__bf16)a.x; v[1] = (__bf16)a.y; v[2] = (__bf16)a.z; v[3] = (__bf16)a.w;
  v[4] = (__bf16)b.x; v[5] = (__bf16)b.y; v[6] = (__bf16)b.z; v[7] = (__bf16)b.w;
  return v;
}

// ---------------- prep: f32->bf16 convert + zero accumulators + decode keys -
__global__ void prep_kernel(const float* __restrict__ emb,
                            const void* __restrict__ rel_raw,
                            const void* __restrict__ ist_raw,
                            __bf16* __restrict__ embB,
                            float* __restrict__ sum_exp,
                            float* __restrict__ numer,
                            int* __restrict__ key) {
  int tid = blockIdx.x * 256 + threadIdx.x;
  size_t base = (size_t)tid * 8;
  if (base < (size_t)NB * ND) {
    float4 a = *(const float4*)(emb + base);
    float4 b = *(const float4*)(emb + base + 4);
    *(bf16x8*)(embB + base) = cvt8(a, b);
  }
  if (tid < NB) { sum_exp[tid] = 0.f; numer[tid] = 0.f; }
  __shared__ int s_rel64, s_bmode;
  if (blockIdx.x < 32) {                 // block-uniform branch
    if (threadIdx.x == 0) {
      int a, b; detect_formats(rel_raw, ist_raw, a, b);
      s_rel64 = a; s_bmode = b;
    }
    __syncthreads();
    int i = blockIdx.x * 256 + threadIdx.x;   // < 8192
    key[i] = decode_key(rel_raw, ist_raw, s_rel64, s_bmode, i);
  }
}

// small-ws fallback prep (no bf16 buffer)
__global__ void prep_small_kernel(const void* __restrict__ rel_raw,
                                  const void* __restrict__ ist_raw,
                                  float* __restrict__ sum_exp,
                                  float* __restrict__ numer,
                                  int* __restrict__ key) {
  int i = blockIdx.x * 256 + threadIdx.x;     // 32 blocks -> 8192
  sum_exp[i] = 0.f; numer[i] = 0.f;
  __shared__ int s_rel64, s_bmode;
  if (threadIdx.x == 0) {
    int a, b; detect_formats(rel_raw, ist_raw, a, b);
    s_rel64 = a; s_bmode = b;
  }
  __syncthreads();
  key[i] = decode_key(rel_raw, ist_raw, s_rel64, s_bmode, i);
}

// ============================================================================
// Fused symmetric GEMM, tail-free grid packing.
// Inner loop identical to round 5 (BK=32 dbuf, swizzled LDS, 4 blocks/CU).
// Grid = 2016 blocks on 1024 block-slots:
//   bid 0..63   : HEAVY — 2 passes: off-diag tile q=1952+bid, then diag
//                 tile (bid,bid).  Dispatched first -> finish ~2*tau.
//   bid 64..2015: LIGHT — 1 pass: strict-lower off-diag tile, XCD-swizzled
//                 (1952 = 8*244, bijective).
// Packing: 960 lights finish at tau, 992 more at 2*tau, heavies at 2*tau ->
// zero tail (was: 32-block straggler tail = 1/3 of the dispatch).
// ============================================================================

__device__ __forceinline__ int decode_bx(int q) {
  int bx = (int)((1.f + sqrtf(1.f + 8.f * (float)q)) * 0.5f);
  while (bx * (bx - 1) / 2 > q) --bx;
  while ((bx + 1) * bx / 2 <= q) ++bx;
  return bx;
}

__global__ __launch_bounds__(256, 4)
void gemm_db_kernel(const __bf16* __restrict__ embB,
                    const int* __restrict__ key,
                    float* __restrict__ sum_exp,
                    float* __restrict__ numer) {
  __shared__ __bf16 sT[2][2][8 * 512];   // [buf][op A=0/B=1][band*512]  32 KB
  __shared__ int keyR[128], keyC[128];

  const int bid = blockIdx.x;
  int rb0, cb0, npass;
  if (bid < 64) {
    int q = 1952 + bid;                  // one of the last 64 off-diag tiles
    int bx = decode_bx(q);
    int by = q - bx * (bx - 1) / 2;
    rb0 = by * 128; cb0 = bx * 128;
    npass = 2;                           // pass 1 = diag tile (bid,bid)
  } else {
    int j = bid - 64;
    int q = (j & 7) * 244 + (j >> 3);    // XCD-chunked bijective swizzle
    int bx = decode_bx(q);
    int by = q - bx * (bx - 1) / 2;
    rb0 = by * 128; cb0 = bx * 128;
    npass = 1;
  }

  const int tid = threadIdx.x;
  const int wid = tid >> 6;     // 0..3
  const int l   = tid & 63;
  const int wr  = wid >> 1;     // wave row (0..1)
  const int wc  = wid & 1;      // wave col (0..1)
  // swizzled fragment offset within a [16][32] subtile (elements)
  const int fragOff = ((l & 15) << 5) + ((((l >> 4)) ^ ((l >> 1) & 3)) << 3);
  // staging source coords (inverse involution, LDS dest stays linear)
  const int srow = l >> 2;
  const int scol = ((l & 3) ^ ((l >> 3) & 3)) << 3;

#pragma unroll 1
  for (int p = 0; p < npass; ++p) {
    const bool diag = (p != 0);          // pass 1 is always the diag tile
    const int rowBase = diag ? bid * 128 : rb0;
    const int colBase = diag ? bid * 128 : cb0;

    __syncthreads();   // protect keyR/keyC (read by prev pass's epilogue)
    if (tid < 128) keyR[tid] = key[rowBase + tid];
    else           keyC[tid - 128] = key[colBase + tid - 128];

    // prologue: stage K-tile 0 into buf 0 (each wave: 2 A-bands + 2 B-bands)
#pragma unroll
    for (int s = 0; s < 2; ++s) {
      int band = wid * 2 + s;    // 0..7
      const __bf16* sa = embB + (size_t)(rowBase + band * 16 + srow) * ND + scol;
      const __bf16* sb = embB + (size_t)(colBase + band * 16 + srow) * ND + scol;
      __builtin_amdgcn_global_load_lds(
          (const __attribute__((address_space(1))) void*)sa,
          (__attribute__((address_space(3))) void*)&sT[0][0][band * 512], 16, 0, 0);
      __builtin_amdgcn_global_load_lds(
          (const __attribute__((address_space(1))) void*)sb,
          (__attribute__((address_space(3))) void*)&sT[0][1][band * 512], 16, 0, 0);
    }

    f32x4 acc[4][4] = {};

    for (int kt = 0; kt < 32; ++kt) {
      __syncthreads();   // drains vmcnt (staged tile kt landed) + prior LDS ops
      if (kt < 31) {     // stage K-tile kt+1 into the other buffer
        int k0 = (kt + 1) * 32;
        int nb = (kt + 1) & 1;
#pragma unroll
        for (int s = 0; s < 2; ++s) {
          int band = wid * 2 + s;
          const __bf16* sa = embB + (size_t)(rowBase + band * 16 + srow) * ND + k0 + scol;
          const __bf16* sb = embB + (size_t)(colBase + band * 16 + srow) * ND + k0 + scol;
          __builtin_amdgcn_global_load_lds(
              (const __attribute__((address_space(1))) void*)sa,
              (__attribute__((address_space(3))) void*)&sT[nb][0][band * 512], 16, 0, 0);
          __builtin_amdgcn_global_load_lds(
              (const __attribute__((address_space(1))) void*)sb,
              (__attribute__((address_space(3))) void*)&sT[nb][1][band * 512], 16, 0, 0);
        }
      }
      const __bf16* cA = &sT[kt & 1][0][0];
      const __bf16* cB = &sT[kt & 1][1][0];
      bf16x8 af[4], bfr[4];
#pragma unroll
      for (int m = 0; m < 4; ++m)
        af[m] = *(const bf16x8*)&cA[(wr * 4 + m) * 512 + fragOff];
#pragma unroll
      for (int n = 0; n < 4; ++n)
        bfr[n] = *(const bf16x8*)&cB[(wc * 4 + n) * 512 + fragOff];
#pragma unroll
      for (int m = 0; m < 4; ++m)
#pragma unroll
        for (int n = 0; n < 4; ++n)
          acc[m][n] = __builtin_amdgcn_mfma_f32_16x16x32_bf16(af[m], bfr[n], acc[m][n], 0, 0, 0);
    }

    // epilogue: C/D layout col = lane&15, row = (lane>>4)*4 + reg
    float cse[4] = {0.f, 0.f, 0.f, 0.f};   // per-col partials (off-diag only)
    float cnu[4] = {0.f, 0.f, 0.f, 0.f};
#pragma unroll
    for (int m = 0; m < 4; ++m) {
#pragma unroll
      for (int r4 = 0; r4 < 4; ++r4) {
        int li = wr * 64 + m * 16 + (l >> 4) * 4 + r4;
        int gi = rowBase + li;
        int krow = keyR[li];
        float se = 0.f, nu = 0.f;
#pragma unroll
        for (int n = 0; n < 4; ++n) {
          int lj = wc * 64 + n * 16 + (l & 15);
          int gj = colBase + lj;
          float e = __expf(acc[m][n][r4] * SCALE);
          if (gi == gj) e = 0.f;          // only possible on diagonal tiles
          bool match = (krow >= 0) && (krow == keyC[lj]);
          se += e;
          if (match) nu += e;
          if (!diag) {
            cse[n] += e;
            if (match) cnu[n] += e;
          }
        }
#pragma unroll
        for (int off = 8; off; off >>= 1) {
          se += __shfl_xor(se, off, 16);
          nu += __shfl_xor(nu, off, 16);
        }
        if ((l & 15) == 0) {
          atomicAdd(&sum_exp[gi], se);
          if (nu != 0.f) atomicAdd(&numer[gi], nu);
        }
      }
    }
    if (!diag) {
#pragma unroll
      for (int n = 0; n < 4; ++n) {
        cse[n] += __shfl_xor(cse[n], 16);
        cse[n] += __shfl_xor(cse[n], 32);
        cnu[n] += __shfl_xor(cnu[n], 16);
        cnu[n] += __shfl_xor(cnu[n], 32);
      }
      if (l < 16) {
#pragma unroll
        for (int n = 0; n < 4; ++n) {
          int gj = colBase + wc * 64 + n * 16 + l;
          atomicAdd(&sum_exp[gj], cse[n]);
          if (cnu[n] != 0.f) atomicAdd(&numer[gj], cnu[n]);
        }
      }
    }
  }
}

// ---------------- fallback 128^2 fused kernel (small-ws path) --------------
__global__ __launch_bounds__(256, 4)
void gemm_fused_f32_kernel(const float* __restrict__ embF,
                           const int* __restrict__ key,
                           float* __restrict__ sum_exp,
                           float* __restrict__ numer) {
  __shared__ __bf16 sA[128 * 64];
  __shared__ __bf16 sB[128 * 64];
  __shared__ int keyR[128], keyC[128];

  const int t = blockIdx.x;
  int r = (int)((sqrtf(8.f * (float)t + 1.f) - 1.f) * 0.5f);
  while ((r + 1) * (r + 2) / 2 <= t) ++r;
  while (r * (r + 1) / 2 > t) --r;
  const int bx = r;
  const int by = t - r * (r + 1) / 2;
  const bool diag = (bx == by);

  const int tid = threadIdx.x;
  const int wid = tid >> 6;
  const int l   = tid & 63;
  const int wr  = wid >> 1;
  const int wc  = wid & 1;
  const int rowBase = by * 128;
  const int colBase = bx * 128;

  if (tid < 128) keyR[tid] = key[rowBase + tid];
  else           keyC[tid - 128] = key[colBase + tid - 128];

  f32x4 acc[4][4] = {};

  for (int k0 = 0; k0 < ND; k0 += 64) {
    __syncthreads();
#pragma unroll
    for (int c = 0; c < 4; ++c) {
      int chunk = tid + c * 256;
      int row = chunk >> 3;
      int ko  = (chunk & 7) * 8;
      const float* gfa = embF + (size_t)(rowBase + row) * ND + k0 + ko;
      const float* gfb = embF + (size_t)(colBase + row) * ND + k0 + ko;
      float4 a0 = *(const float4*)gfa;
      float4 a1 = *(const float4*)(gfa + 4);
      float4 b0 = *(const float4*)gfb;
      float4 b1 = *(const float4*)(gfb + 4);
      *(bf16x8*)&sA[row * 64 + ko] = cvt8(a0, a1);
      *(bf16x8*)&sB[row * 64 + ko] = cvt8(b0, b1);
    }
    __syncthreads();

#pragma unroll
    for (int kk = 0; kk < 2; ++kk) {
      bf16x8 af[4], bfr[4];
#pragma unroll
      for (int m = 0; m < 4; ++m)
        af[m] = *(const bf16x8*)&sA[(wr * 64 + m * 16 + (l & 15)) * 64 + kk * 32 + (l >> 4) * 8];
#pragma unroll
      for (int n = 0; n < 4; ++n)
        bfr[n] = *(const bf16x8*)&sB[(wc * 64 + n * 16 + (l & 15)) * 64 + kk * 32 + (l >> 4) * 8];
#pragma unroll
      for (int m = 0; m < 4; ++m)
#pragma unroll
        for (int n = 0; n < 4; ++n)
          acc[m][n] = __builtin_amdgcn_mfma_f32_16x16x32_bf16(af[m], bfr[n], acc[m][n], 0, 0, 0);
    }
  }

  float cse[4] = {0.f, 0.f, 0.f, 0.f};
  float cnu[4] = {0.f, 0.f, 0.f, 0.f};
#pragma unroll
  for (int m = 0; m < 4; ++m) {
#pragma unroll
    for (int r4 = 0; r4 < 4; ++r4) {
      int li = wr * 64 + m * 16 + (l >> 4) * 4 + r4;
      int gi = rowBase + li;
      int krow = keyR[li];
      float se = 0.f, nu = 0.f;
#pragma unroll
      for (int n = 0; n < 4; ++n) {
        int lj = wc * 64 + n * 16 + (l & 15);
        int gj = colBase + lj;
        float e = __expf(acc[m][n][r4] * SCALE);
        if (gi == gj) e = 0.f;
        bool match = (krow >= 0) && (krow == keyC[lj]);
        se += e;
        if (match) nu += e;
        if (!diag) {
          cse[n] += e;
          if (match) cnu[n] += e;
        }
      }
#pragma unroll
      for (int off = 8; off; off >>= 1) {
        se += __shfl_xor(se, off, 16);
        nu += __shfl_xor(nu, off, 16);
      }
      if ((l & 15) == 0) {
        atomicAdd(&sum_exp[gi], se);
        if (nu != 0.f) atomicAdd(&numer[gi], nu);
      }
    }
  }
  if (!diag) {
#pragma unroll
    for (int n = 0; n < 4; ++n) {
      cse[n] += __shfl_xor(cse[n], 16);
      cse[n] += __shfl_xor(cse[n], 32);
      cnu[n] += __shfl_xor(cnu[n], 16);
      cnu[n] += __shfl_xor(cnu[n], 32);
    }
    if (l < 16) {
#pragma unroll
      for (int n = 0; n < 4; ++n) {
        int gj = colBase + wc * 64 + n * 16 + l;
        atomicAdd(&sum_exp[gj], cse[n]);
        if (cnu[n] != 0.f) atomicAdd(&numer[gj], cnu[n]);
      }
    }
  }
}

// ---------------- finalize: histogram -> has_pos, losses, reductions -------
__global__ void finalize_kernel(const float* __restrict__ sum_exp,
                                const float* __restrict__ numer,
                                const int* __restrict__ key,
                                float* __restrict__ out) {
  __shared__ int cnt[128];
  __shared__ float wsum[16];
  __shared__ int wcnt[16];
  int tid = threadIdx.x;      // 1024 threads
  if (tid < 128) cnt[tid] = 0;
  __syncthreads();
  for (int i = tid; i < NB; i += 1024) {
    int k = key[i];
    if (k >= 0) atomicAdd(&cnt[k], 1);
  }
  __syncthreads();
  float ls = 0.f; int np = 0;
  for (int i = tid; i < NB; i += 1024) {
    int k = key[i];
    if (k >= 0 && cnt[k] >= 2) {
      np++;
      ls += logf(sum_exp[i] + 1e-8f) - logf(numer[i]);
    }
  }
  for (int off = 32; off; off >>= 1) {
    ls += __shfl_down(ls, off, 64);
    np += __shfl_down(np, off, 64);
  }
  int w = tid >> 6;
  if ((tid & 63) == 0) { wsum[w] = ls; wcnt[w] = np; }
  __syncthreads();
  if (tid == 0) {
    float s = 0.f; int n = 0;
    for (int i = 0; i < 16; ++i) { s += wsum[i]; n += wcnt[i]; }
    out[0] = (n > 0) ? (s / (float)n) : 0.f;
    out[1] = (float)n;
  }
}

// ---------------------------------------------------------------------------
#define NGRID 2016                         // 64 heavy (2 tiles) + 1952 light
#define NT128 64
#define NTRI128 (NT128 * (NT128 + 1) / 2)  // 2080 (fallback path)

extern "C" void kernel_launch(void* const* d_in, const int* in_sizes, int n_in,
                              void* d_out, int out_size, void* d_ws, size_t ws_size,
                              hipStream_t stream) {
  const float* emb = (const float*)d_in[0];
  const void* rel  = d_in[1];
  const void* ist  = d_in[2];
  float* out = (float*)d_out;

  const size_t embBytes = (size_t)NB * ND * sizeof(__bf16);   // 16 MiB
  const size_t smallBytes = (size_t)NB * 4 * 3;               // 96 KiB

  char* ws = (char*)d_ws;
  if (ws_size >= embBytes + smallBytes) {
    __bf16* embB   = (__bf16*)ws;
    float* sum_exp = (float*)(ws + embBytes);
    float* numer   = sum_exp + NB;
    int*   key     = (int*)(numer + NB);
    prep_kernel<<<4096, 256, 0, stream>>>(emb, rel, ist, embB, sum_exp, numer, key);
    gemm_db_kernel<<<NGRID, 256, 0, stream>>>(embB, key, sum_exp, numer);
    finalize_kernel<<<1, 1024, 0, stream>>>(sum_exp, numer, key, out);
  } else {
    float* sum_exp = (float*)ws;
    float* numer   = sum_exp + NB;
    int*   key     = (int*)(numer + NB);
    prep_small_kernel<<<32, 256, 0, stream>>>(rel, ist, sum_exp, numer, key);
    gemm_fused_f32_kernel<<<NTRI128, 256, 0, stream>>>(emb, key, sum_exp, numer);
    finalize_kernel<<<1, 1024, 0, stream>>>(sum_exp, numer, key, out);
  }
}

// Round 7
// 131.695 us; speedup vs baseline: 1.0519x; 1.0519x over previous
//
#include <hip/hip_runtime.h>
#include <hip/hip_bf16.h>
#include <hip/hip_fp8.h>
#include <stdint.h>

#define NB 8192
#define ND 1024
#define SCALE 20.0f        // 1/TEMPERATURE
#define PRESCALE 16.0f     // fp8 pre-scale; sim comes out x256
#define EXPSCALE (SCALE / (PRESCALE * PRESCALE))

typedef __bf16 bf16x8 __attribute__((ext_vector_type(8)));
typedef float  f32x4  __attribute__((ext_vector_type(4)));

// ---------------- input-format detection (device-side, deterministic) -------
__device__ inline void detect_formats(const void* rel_raw, const void* ist_raw,
                                      int& rel64, int& bmode) {
  const unsigned int* r = (const unsigned int*)rel_raw;
  int is64 = 1;
  for (int i = 1; i < 256; i += 2) {
    if (r[i] != 0u) { is64 = 0; break; }
  }
  rel64 = is64;
  const unsigned int* t = (const unsigned int*)ist_raw;
  bool sawf = false, sawbig = false;
  for (int i = 0; i < 64; ++i) {
    unsigned int w = t[i];
    if (w == 0x3F800000u) sawf = true;
    else if (w > 1u) sawbig = true;
  }
  bmode = sawf ? 2 : (sawbig ? 1 : 0);
}

__device__ inline int decode_key(const void* rel_raw, const void* ist_raw,
                                 int rel64, int bmode, int i) {
  const int* r32 = (const int*)rel_raw;
  int r = rel64 ? r32[2 * i] : r32[i];
  int truth;
  if (bmode == 1)      truth = (((const unsigned char*)ist_raw)[i] != 0);
  else if (bmode == 2) truth = (((const float*)ist_raw)[i] != 0.0f);
  else                 truth = (((const int*)ist_raw)[i] != 0);
  return truth ? r : -1;
}

__device__ inline bf16x8 cvt8(const float4& a, const float4& b) {
  bf16x8 v;
  v[0] = (__bf16)a.x; v[1] = (__bf16)a.y; v[2] = (__bf16)a.z; v[3] = (__bf16)a.w;
  v[4] = (__bf16)b.x; v[5] = (__bf16)b.y; v[6] = (__bf16)b.z; v[7] = (__bf16)b.w;
  return v;
}

__device__ inline unsigned long long cvt8f8(const float4& a, const float4& b) {
  float v[8] = {a.x, a.y, a.z, a.w, b.x, b.y, b.z, b.w};
  unsigned long long pk = 0;
#pragma unroll
  for (int i = 0; i < 8; ++i) {
    __hip_fp8_e4m3 h(v[i] * PRESCALE);
    pk |= (unsigned long long)(unsigned char)h.__x << (8 * i);
  }
  return pk;
}

// ---------------- prep: f32->fp8 convert + zero accumulators + decode keys --
__global__ void prep_kernel(const float* __restrict__ emb,
                            const void* __restrict__ rel_raw,
                            const void* __restrict__ ist_raw,
                            unsigned char* __restrict__ emb8,
                            float* __restrict__ sum_exp,
                            float* __restrict__ numer,
                            int* __restrict__ key) {
  int tid = blockIdx.x * 256 + threadIdx.x;
  size_t base = (size_t)tid * 8;
  if (base < (size_t)NB * ND) {
    float4 a = *(const float4*)(emb + base);
    float4 b = *(const float4*)(emb + base + 4);
    *(unsigned long long*)(emb8 + base) = cvt8f8(a, b);
  }
  if (tid < NB) { sum_exp[tid] = 0.f; numer[tid] = 0.f; }
  __shared__ int s_rel64, s_bmode;
  if (blockIdx.x < 32) {                 // block-uniform branch
    if (threadIdx.x == 0) {
      int a, b; detect_formats(rel_raw, ist_raw, a, b);
      s_rel64 = a; s_bmode = b;
    }
    __syncthreads();
    int i = blockIdx.x * 256 + threadIdx.x;   // < 8192
    key[i] = decode_key(rel_raw, ist_raw, s_rel64, s_bmode, i);
  }
}

// small-ws fallback prep (no fp8 buffer)
__global__ void prep_small_kernel(const void* __restrict__ rel_raw,
                                  const void* __restrict__ ist_raw,
                                  float* __restrict__ sum_exp,
                                  float* __restrict__ numer,
                                  int* __restrict__ key) {
  int i = blockIdx.x * 256 + threadIdx.x;     // 32 blocks -> 8192
  sum_exp[i] = 0.f; numer[i] = 0.f;
  __shared__ int s_rel64, s_bmode;
  if (threadIdx.x == 0) {
    int a, b; detect_formats(rel_raw, ist_raw, a, b);
    s_rel64 = a; s_bmode = b;
  }
  __syncthreads();
  key[i] = decode_key(rel_raw, ist_raw, s_rel64, s_bmode, i);
}

// ============================================================================
// Fused symmetric GEMM, fp8-e4m3 operands (half the staged/LDS bytes of r5).
// Structure identical to round 5: 128x128 tile, 4 waves (2x2), BK=32
// double-buffered, ONE __syncthreads per K-tile, 4 blocks/CU.
// LDS per op per buf: [8 bands][16 rows][32 k] fp8 = 4 KB; 16B-block
// swizzle within a row (blk ^= row&1) applied identically on the staging
// source and the ds_read offset (both-sides involution, rule 21).
// MFMA: v_mfma_f32_16x16x32_fp8_fp8, one per (m,n) frag per kt.
// ============================================================================

__global__ __launch_bounds__(256, 4)
void gemm_f8_kernel(const unsigned char* __restrict__ emb8,
                    const int* __restrict__ key,
                    float* __restrict__ sum_exp,
                    float* __restrict__ numer) {
  __shared__ unsigned char sT[2][2][8 * 512];   // [buf][op A=0/B=1]  16 KB
  __shared__ int keyR[128], keyC[128];

  // XCD-chunked bijective swizzle (2080 = 8 * 260), then triangular decode
  const int bid = blockIdx.x;
  const int t = (bid & 7) * 260 + (bid >> 3);
  int r = (int)((sqrtf(8.f * (float)t + 1.f) - 1.f) * 0.5f);
  while ((r + 1) * (r + 2) / 2 <= t) ++r;
  while (r * (r + 1) / 2 > t) --r;
  const int bx = r, by = t - r * (r + 1) / 2;
  const bool diag = (bx == by);
  const int rowBase = by * 128, colBase = bx * 128;

  const int tid = threadIdx.x;
  const int wid = tid >> 6;     // 0..3
  const int l   = tid & 63;
  const int wr  = wid >> 1;     // wave row (0..1)
  const int wc  = wid & 1;      // wave col (0..1)
  // swizzled fragment byte offset within a [16][32] fp8 subtile:
  // row=l&15 (32B each), 16B-block ((l>>5) ^ (row&1)), 8B half (l>>4)&1
  const int fragOff = ((l & 15) << 5) + ((((l >> 5)) ^ (l & 1)) << 4) + (((l >> 4) & 1) << 3);
  // staging source coords (same involution; LDS dest stays lane-linear)
  const int sband = l >> 5;            // sub-band within the wave's 2 bands
  const int srow  = (l >> 1) & 15;
  const int scol  = (((l & 1) ^ ((l >> 1) & 1)) << 4);

  if (tid < 128) keyR[tid] = key[rowBase + tid];
  else           keyC[tid - 128] = key[colBase + tid - 128];

  // prologue: stage K-tile 0 into buf 0 (each wave: 2 A-bands + 2 B-bands,
  // one 64-lane global_load_lds per operand)
  {
    const unsigned char* sa = emb8 + (size_t)(rowBase + (wid * 2 + sband) * 16 + srow) * ND + scol;
    const unsigned char* sb = emb8 + (size_t)(colBase + (wid * 2 + sband) * 16 + srow) * ND + scol;
    __builtin_amdgcn_global_load_lds(
        (const __attribute__((address_space(1))) void*)sa,
        (__attribute__((address_space(3))) void*)&sT[0][0][wid * 1024], 16, 0, 0);
    __builtin_amdgcn_global_load_lds(
        (const __attribute__((address_space(1))) void*)sb,
        (__attribute__((address_space(3))) void*)&sT[0][1][wid * 1024], 16, 0, 0);
  }

  f32x4 acc[4][4] = {};

  for (int kt = 0; kt < 32; ++kt) {
    __syncthreads();   // drains vmcnt (staged tile kt landed) + prior LDS ops
    if (kt < 31) {     // stage K-tile kt+1 into the other buffer
      int k0 = (kt + 1) * 32;
      int nb = (kt + 1) & 1;
      const unsigned char* sa = emb8 + (size_t)(rowBase + (wid * 2 + sband) * 16 + srow) * ND + k0 + scol;
      const unsigned char* sb = emb8 + (size_t)(colBase + (wid * 2 + sband) * 16 + srow) * ND + k0 + scol;
      __builtin_amdgcn_global_load_lds(
          (const __attribute__((address_space(1))) void*)sa,
          (__attribute__((address_space(3))) void*)&sT[nb][0][wid * 1024], 16, 0, 0);
      __builtin_amdgcn_global_load_lds(
          (const __attribute__((address_space(1))) void*)sb,
          (__attribute__((address_space(3))) void*)&sT[nb][1][wid * 1024], 16, 0, 0);
    }
    const unsigned char* cA = &sT[kt & 1][0][0];
    const unsigned char* cB = &sT[kt & 1][1][0];
    long af[4], bfr[4];
#pragma unroll
    for (int m = 0; m < 4; ++m)
      af[m] = *(const long*)&cA[((wr * 4 + m) << 9) + fragOff];
#pragma unroll
    for (int n = 0; n < 4; ++n)
      bfr[n] = *(const long*)&cB[((wc * 4 + n) << 9) + fragOff];
#pragma unroll
    for (int m = 0; m < 4; ++m)
#pragma unroll
      for (int n = 0; n < 4; ++n)
        acc[m][n] = __builtin_amdgcn_mfma_f32_16x16x32_fp8_fp8(af[m], bfr[n], acc[m][n], 0, 0, 0);
  }

  // epilogue: C/D layout col = lane&15, row = (lane>>4)*4 + reg
  float cse[4] = {0.f, 0.f, 0.f, 0.f};   // per-col partials (off-diag only)
  float cnu[4] = {0.f, 0.f, 0.f, 0.f};
#pragma unroll
  for (int m = 0; m < 4; ++m) {
#pragma unroll
    for (int r4 = 0; r4 < 4; ++r4) {
      int li = wr * 64 + m * 16 + (l >> 4) * 4 + r4;
      int gi = rowBase + li;
      int krow = keyR[li];
      float se = 0.f, nu = 0.f;
#pragma unroll
      for (int n = 0; n < 4; ++n) {
        int lj = wc * 64 + n * 16 + (l & 15);
        int gj = colBase + lj;
        float e = __expf(acc[m][n][r4] * EXPSCALE);
        if (gi == gj) e = 0.f;          // only possible on diagonal tiles
        bool match = (krow >= 0) && (krow == keyC[lj]);
        se += e;
        if (match) nu += e;
        if (!diag) {
          cse[n] += e;
          if (match) cnu[n] += e;
        }
      }
#pragma unroll
      for (int off = 8; off; off >>= 1) {
        se += __shfl_xor(se, off, 16);
        nu += __shfl_xor(nu, off, 16);
      }
      if ((l & 15) == 0) {
        atomicAdd(&sum_exp[gi], se);
        if (nu != 0.f) atomicAdd(&numer[gi], nu);
      }
    }
  }
  if (!diag) {
#pragma unroll
    for (int n = 0; n < 4; ++n) {
      cse[n] += __shfl_xor(cse[n], 16);
      cse[n] += __shfl_xor(cse[n], 32);
      cnu[n] += __shfl_xor(cnu[n], 16);
      cnu[n] += __shfl_xor(cnu[n], 32);
    }
    if (l < 16) {
#pragma unroll
      for (int n = 0; n < 4; ++n) {
        int gj = colBase + wc * 64 + n * 16 + l;
        atomicAdd(&sum_exp[gj], cse[n]);
        if (cnu[n] != 0.f) atomicAdd(&numer[gj], cnu[n]);
      }
    }
  }
}

// ---------------- fallback 128^2 fused kernel (small-ws path, bf16) --------
__global__ __launch_bounds__(256, 4)
void gemm_fused_f32_kernel(const float* __restrict__ embF,
                           const int* __restrict__ key,
                           float* __restrict__ sum_exp,
                           float* __restrict__ numer) {
  __shared__ __bf16 sA[128 * 64];
  __shared__ __bf16 sB[128 * 64];
  __shared__ int keyR[128], keyC[128];

  const int t = blockIdx.x;
  int r = (int)((sqrtf(8.f * (float)t + 1.f) - 1.f) * 0.5f);
  while ((r + 1) * (r + 2) / 2 <= t) ++r;
  while (r * (r + 1) / 2 > t) --r;
  const int bx = r;
  const int by = t - r * (r + 1) / 2;
  const bool diag = (bx == by);

  const int tid = threadIdx.x;
  const int wid = tid >> 6;
  const int l   = tid & 63;
  const int wr  = wid >> 1;
  const int wc  = wid & 1;
  const int rowBase = by * 128;
  const int colBase = bx * 128;

  if (tid < 128) keyR[tid] = key[rowBase + tid];
  else           keyC[tid - 128] = key[colBase + tid - 128];

  f32x4 acc[4][4] = {};

  for (int k0 = 0; k0 < ND; k0 += 64) {
    __syncthreads();
#pragma unroll
    for (int c = 0; c < 4; ++c) {
      int chunk = tid + c * 256;
      int row = chunk >> 3;
      int ko  = (chunk & 7) * 8;
      const float* gfa = embF + (size_t)(rowBase + row) * ND + k0 + ko;
      const float* gfb = embF + (size_t)(colBase + row) * ND + k0 + ko;
      float4 a0 = *(const float4*)gfa;
      float4 a1 = *(const float4*)(gfa + 4);
      float4 b0 = *(const float4*)gfb;
      float4 b1 = *(const float4*)(gfb + 4);
      *(bf16x8*)&sA[row * 64 + ko] = cvt8(a0, a1);
      *(bf16x8*)&sB[row * 64 + ko] = cvt8(b0, b1);
    }
    __syncthreads();

#pragma unroll
    for (int kk = 0; kk < 2; ++kk) {
      bf16x8 af[4], bfr[4];
#pragma unroll
      for (int m = 0; m < 4; ++m)
        af[m] = *(const bf16x8*)&sA[(wr * 64 + m * 16 + (l & 15)) * 64 + kk * 32 + (l >> 4) * 8];
#pragma unroll
      for (int n = 0; n < 4; ++n)
        bfr[n] = *(const bf16x8*)&sB[(wc * 64 + n * 16 + (l & 15)) * 64 + kk * 32 + (l >> 4) * 8];
#pragma unroll
      for (int m = 0; m < 4; ++m)
#pragma unroll
        for (int n = 0; n < 4; ++n)
          acc[m][n] = __builtin_amdgcn_mfma_f32_16x16x32_bf16(af[m], bfr[n], acc[m][n], 0, 0, 0);
    }
  }

  float cse[4] = {0.f, 0.f, 0.f, 0.f};
  float cnu[4] = {0.f, 0.f, 0.f, 0.f};
#pragma unroll
  for (int m = 0; m < 4; ++m) {
#pragma unroll
    for (int r4 = 0; r4 < 4; ++r4) {
      int li = wr * 64 + m * 16 + (l >> 4) * 4 + r4;
      int gi = rowBase + li;
      int krow = keyR[li];
      float se = 0.f, nu = 0.f;
#pragma unroll
      for (int n = 0; n < 4; ++n) {
        int lj = wc * 64 + n * 16 + (l & 15);
        int gj = colBase + lj;
        float e = __expf(acc[m][n][r4] * SCALE);
        if (gi == gj) e = 0.f;
        bool match = (krow >= 0) && (krow == keyC[lj]);
        se += e;
        if (match) nu += e;
        if (!diag) {
          cse[n] += e;
          if (match) cnu[n] += e;
        }
      }
#pragma unroll
      for (int off = 8; off; off >>= 1) {
        se += __shfl_xor(se, off, 16);
        nu += __shfl_xor(nu, off, 16);
      }
      if ((l & 15) == 0) {
        atomicAdd(&sum_exp[gi], se);
        if (nu != 0.f) atomicAdd(&numer[gi], nu);
      }
    }
  }
  if (!diag) {
#pragma unroll
    for (int n = 0; n < 4; ++n) {
      cse[n] += __shfl_xor(cse[n], 16);
      cse[n] += __shfl_xor(cse[n], 32);
      cnu[n] += __shfl_xor(cnu[n], 16);
      cnu[n] += __shfl_xor(cnu[n], 32);
    }
    if (l < 16) {
#pragma unroll
      for (int n = 0; n < 4; ++n) {
        int gj = colBase + wc * 64 + n * 16 + l;
        atomicAdd(&sum_exp[gj], cse[n]);
        if (cnu[n] != 0.f) atomicAdd(&numer[gj], cnu[n]);
      }
    }
  }
}

// ---------------- finalize: histogram -> has_pos, losses, reductions -------
__global__ void finalize_kernel(const float* __restrict__ sum_exp,
                                const float* __restrict__ numer,
                                const int* __restrict__ key,
                                float* __restrict__ out) {
  __shared__ int cnt[128];
  __shared__ float wsum[16];
  __shared__ int wcnt[16];
  int tid = threadIdx.x;      // 1024 threads
  if (tid < 128) cnt[tid] = 0;
  __syncthreads();
  for (int i = tid; i < NB; i += 1024) {
    int k = key[i];
    if (k >= 0) atomicAdd(&cnt[k], 1);
  }
  __syncthreads();
  float ls = 0.f; int np = 0;
  for (int i = tid; i < NB; i += 1024) {
    int k = key[i];
    if (k >= 0 && cnt[k] >= 2) {
      np++;
      ls += logf(sum_exp[i] + 1e-8f) - logf(numer[i]);
    }
  }
  for (int off = 32; off; off >>= 1) {
    ls += __shfl_down(ls, off, 64);
    np += __shfl_down(np, off, 64);
  }
  int w = tid >> 6;
  if ((tid & 63) == 0) { wsum[w] = ls; wcnt[w] = np; }
  __syncthreads();
  if (tid == 0) {
    float s = 0.f; int n = 0;
    for (int i = 0; i < 16; ++i) { s += wsum[i]; n += wcnt[i]; }
    out[0] = (n > 0) ? (s / (float)n) : 0.f;
    out[1] = (float)n;
  }
}

// ---------------------------------------------------------------------------
#define NT128 64
#define NTRI128 (NT128 * (NT128 + 1) / 2) // 2080

extern "C" void kernel_launch(void* const* d_in, const int* in_sizes, int n_in,
                              void* d_out, int out_size, void* d_ws, size_t ws_size,
                              hipStream_t stream) {
  const float* emb = (const float*)d_in[0];
  const void* rel  = d_in[1];
  const void* ist  = d_in[2];
  float* out = (float*)d_out;

  const size_t emb8Bytes = (size_t)NB * ND;      // 8 MiB fp8
  const size_t smallBytes = (size_t)NB * 4 * 3;  // 96 KiB

  char* ws = (char*)d_ws;
  if (ws_size >= emb8Bytes + smallBytes) {
    unsigned char* emb8 = (unsigned char*)ws;
    float* sum_exp = (float*)(ws + emb8Bytes);
    float* numer   = sum_exp + NB;
    int*   key     = (int*)(numer + NB);
    prep_kernel<<<4096, 256, 0, stream>>>(emb, rel, ist, emb8, sum_exp, numer, key);
    gemm_f8_kernel<<<NTRI128, 256, 0, stream>>>(emb8, key, sum_exp, numer);
    finalize_kernel<<<1, 1024, 0, stream>>>(sum_exp, numer, key, out);
  } else {
    float* sum_exp = (float*)ws;
    float* numer   = sum_exp + NB;
    int*   key     = (int*)(numer + NB);
    prep_small_kernel<<<32, 256, 0, stream>>>(rel, ist, sum_exp, numer, key);
    gemm_fused_f32_kernel<<<NTRI128, 256, 0, stream>>>(emb, key, sum_exp, numer);
    finalize_kernel<<<1, 1024, 0, stream>>>(sum_exp, numer, key, out);
  }
}